// Round 1
// baseline (4664.054 us; speedup 1.0000x reference)
//
#include <hip/hip_runtime.h>
#include <math.h>

#define HH 256
#define NCC 128
#define SPWW 64
#define CST 8192
#define VV 10000
#define BBB 16
#define TTT 256

// ---------------- embeddings ----------------
__global__ __launch_bounds__(256) void fhmm_emb_kernel(
    const float* __restrict__ e1, const float* __restrict__ e2,
    float* __restrict__ out)
{
    int idx = blockIdx.x * 256 + threadIdx.x;   // over 8192*256
    int s = idx >> 8, h = idx & 255;
    out[idx] = e1[(s >> 6) * HH + h] + e2[(s & 63) * HH + h];
}

// ---------------- residual MLP matmul (M=8192, K=N=256) ----------------
__global__ __launch_bounds__(256) void fhmm_mlp_kernel(
    const float* __restrict__ X,
    const float* __restrict__ se1x, const float* __restrict__ se2x,
    const float* __restrict__ W, const float* __restrict__ bias,
    const float* __restrict__ se1r, const float* __restrict__ se2r,
    float* __restrict__ Y, int emb_x, int add_res)
{
    int m0 = blockIdx.x * 64;
    int n0 = blockIdx.y * 64;
    int tid = threadIdx.x;
    __shared__ float Xs[64][65];
    __shared__ float Ws[64][65];
    int ty = tid >> 4, tx = tid & 15;
    float acc[4][4] = {};
    for (int kt = 0; kt < 4; ++kt) {
        __syncthreads();
        for (int i = 0; i < 16; ++i) {
            int idx = tid + i * 256;
            int rl = idx >> 6, cl = idx & 63;
            int gk = kt * 64 + cl;
            int gm = m0 + rl;
            float xv;
            if (emb_x) xv = se1x[(gm >> 6) * HH + gk] + se2x[(gm & 63) * HH + gk];
            else       xv = X[gm * HH + gk];
            Xs[rl][cl] = xv;
            Ws[rl][cl] = W[(kt * 64 + rl) * HH + n0 + cl];
        }
        __syncthreads();
        #pragma unroll
        for (int kk = 0; kk < 64; ++kk) {
            float av[4], bv[4];
            #pragma unroll
            for (int i = 0; i < 4; ++i) av[i] = Xs[ty * 4 + i][kk];
            #pragma unroll
            for (int j = 0; j < 4; ++j) bv[j] = Ws[kk][tx * 4 + j];
            #pragma unroll
            for (int i = 0; i < 4; ++i)
                #pragma unroll
                for (int j = 0; j < 4; ++j)
                    acc[i][j] += av[i] * bv[j];
        }
    }
    #pragma unroll
    for (int i = 0; i < 4; ++i) {
        int gm = m0 + ty * 4 + i;
        #pragma unroll
        for (int j = 0; j < 4; ++j) {
            int gn = n0 + tx * 4 + j;
            float yv = acc[i][j] + bias[gn];
            yv = fmaxf(yv, 0.f);
            if (add_res) yv += se1r[(gm >> 6) * HH + gn] + se2r[(gm & 63) * HH + gn];
            Y[gm * HH + gn] = yv;
        }
    }
}

// ---------------- start head: dot with pw ----------------
__global__ __launch_bounds__(256) void fhmm_dotpw_kernel(
    const float* __restrict__ hstart, const float* __restrict__ pw,
    const float* __restrict__ pbp, float* __restrict__ p)
{
    int wv = threadIdx.x >> 6;
    int lane = threadIdx.x & 63;
    int s = blockIdx.x * 4 + wv;
    const float* hr = hstart + (size_t)s * HH;
    float acc = 0.f;
    #pragma unroll
    for (int i = 0; i < 4; ++i) acc += hr[i * 64 + lane] * pw[i * 64 + lane];
    #pragma unroll
    for (int d = 32; d; d >>= 1) acc += __shfl_xor(acc, d);
    if (lane == 0) p[s] = acc + pbp[0];
}

// ---------------- in-place log_softmax over a length-8192 vector ----------------
__global__ __launch_bounds__(1024) void fhmm_lsm_vec_kernel(float* __restrict__ p)
{
    __shared__ float red[64];
    int tid = threadIdx.x;
    float m = -1e30f;
    for (int i = tid; i < CST; i += 1024) m = fmaxf(m, p[i]);
    #pragma unroll
    for (int d = 32; d; d >>= 1) m = fmaxf(m, __shfl_xor(m, d));
    if ((tid & 63) == 0) red[tid >> 6] = m;
    __syncthreads();
    if (tid == 0) {
        float mm = red[0];
        for (int q = 1; q < 16; ++q) mm = fmaxf(mm, red[q]);
        red[32] = mm;
    }
    __syncthreads();
    float M = red[32];
    float s = 0.f;
    for (int i = tid; i < CST; i += 1024) s += expf(p[i] - M);
    #pragma unroll
    for (int d = 32; d; d >>= 1) s += __shfl_xor(s, d);
    if ((tid & 63) == 0) red[tid >> 6] = s;
    __syncthreads();
    if (tid == 0) {
        float ss = 0.f;
        for (int q = 0; q < 16; ++q) ss += red[q];
        red[33] = ss;
    }
    __syncthreads();
    float lse = M + logf(red[33]);
    for (int i = tid; i < CST; i += 1024) p[i] -= lse;
}

// ---------------- transition row-lse, streaming (no 8192x8192 materialization) ----------------
__global__ __launch_bounds__(256) void fhmm_trans_lse_kernel(
    const float* __restrict__ A,   // h_state 8192x256
    const float* __restrict__ Bm,  // next_emb 8192x256
    float* __restrict__ lse)
{
    int r0 = blockIdx.x * 32;
    int tid = threadIdx.x;
    __shared__ float As[32][257];
    __shared__ float Bs[64][65];
    __shared__ float Cs[32][65];
    __shared__ float mrun[32], srun[32];
    for (int i = 0; i < 32; ++i) {
        int idx = tid + i * 256;
        int rl = idx >> 8, kl = idx & 255;
        As[rl][kl] = A[(size_t)(r0 + rl) * HH + kl];
    }
    if (tid < 32) { mrun[tid] = -1e30f; srun[tid] = 0.f; }
    __syncthreads();

    int ty = tid >> 5;   // 0..7 -> 4 rows each
    int tx = tid & 31;   // 2 cols each
    for (int ct = 0; ct < 128; ++ct) {
        int n0 = ct * 64;
        float acc[4][2] = {};
        for (int kt = 0; kt < 4; ++kt) {
            __syncthreads();
            for (int i = 0; i < 16; ++i) {
                int idx = tid + i * 256;
                int nl = idx >> 6, kl = idx & 63;
                Bs[nl][kl] = Bm[(size_t)(n0 + nl) * HH + kt * 64 + kl];
            }
            __syncthreads();
            #pragma unroll
            for (int kk = 0; kk < 64; ++kk) {
                float bv0 = Bs[tx * 2 + 0][kk];
                float bv1 = Bs[tx * 2 + 1][kk];
                #pragma unroll
                for (int i = 0; i < 4; ++i) {
                    float av = As[ty * 4 + i][kt * 64 + kk];
                    acc[i][0] += av * bv0;
                    acc[i][1] += av * bv1;
                }
            }
        }
        #pragma unroll
        for (int i = 0; i < 4; ++i) {
            Cs[ty * 4 + i][tx * 2 + 0] = acc[i][0];
            Cs[ty * 4 + i][tx * 2 + 1] = acc[i][1];
        }
        __syncthreads();
        int row = tid >> 3, sub = tid & 7;
        float m = -1e30f;
        #pragma unroll
        for (int q = 0; q < 8; ++q) m = fmaxf(m, Cs[row][sub + q * 8]);
        float s = 0.f;
        #pragma unroll
        for (int q = 0; q < 8; ++q) s += expf(Cs[row][sub + q * 8] - m);
        #pragma unroll
        for (int d = 1; d < 8; d <<= 1) {
            float m2 = __shfl_xor(m, d);
            float s2 = __shfl_xor(s, d);
            float Mn = fmaxf(m, m2);
            s = s * expf(m - Mn) + s2 * expf(m2 - Mn);
            m = Mn;
        }
        if (sub == 0) {
            float M = mrun[row], S = srun[row];
            float Mn = fmaxf(M, m);
            srun[row] = S * expf(M - Mn) + s * expf(m - Mn);
            mrun[row] = Mn;
        }
        __syncthreads();
    }
    if (tid < 32) lse[r0 + tid] = mrun[tid] + logf(srun[tid]);
}

// ---------------- per-(b,t) 64x64 transition-logit blocks ----------------
__global__ __launch_bounds__(256) void fhmm_pots_kernel(
    const float* __restrict__ A, const float* __restrict__ Bm,
    const int* __restrict__ text, const int* __restrict__ w2s,
    float* __restrict__ pots)
{
    int blk = blockIdx.x;              // b*255 + t
    int b = blk / (TTT - 1), t = blk % (TTT - 1);
    int v0 = text[b * TTT + t], v1 = text[b * TTT + t + 1];
    int sr = w2s[v0 * SPWW];
    int sc = w2s[v1 * SPWW];
    int tid = threadIdx.x;
    __shared__ float As[64][65];
    __shared__ float Bs[64][65];
    int ty = tid >> 4, tx = tid & 15;
    float acc[4][4] = {};
    for (int kt = 0; kt < 4; ++kt) {
        __syncthreads();
        for (int i = 0; i < 16; ++i) {
            int idx = tid + i * 256;
            int rl = idx >> 6, kl = idx & 63;
            As[rl][kl] = A[(size_t)(sr + rl) * HH + kt * 64 + kl];
            Bs[rl][kl] = Bm[(size_t)(sc + rl) * HH + kt * 64 + kl];
        }
        __syncthreads();
        #pragma unroll
        for (int kk = 0; kk < 64; ++kk) {
            float av[4], bv[4];
            #pragma unroll
            for (int i = 0; i < 4; ++i) av[i] = As[ty * 4 + i][kk];
            #pragma unroll
            for (int j = 0; j < 4; ++j) bv[j] = Bs[tx * 4 + j][kk];
            #pragma unroll
            for (int i = 0; i < 4; ++i)
                #pragma unroll
                for (int j = 0; j < 4; ++j)
                    acc[i][j] += av[i] * bv[j];
        }
    }
    float* outp = pots + (size_t)blk * 4096;
    #pragma unroll
    for (int i = 0; i < 4; ++i)
        #pragma unroll
        for (int j = 0; j < 4; ++j)
            outp[(ty * 4 + i) * 64 + tx * 4 + j] = acc[i][j];
}

// ---------------- emission logits per (word, own 64 states) ----------------
__global__ __launch_bounds__(64) void fhmm_ew_kernel(
    const float* __restrict__ hpre, const float* __restrict__ pw,
    const float* __restrict__ pb, const int* __restrict__ w2s,
    float* __restrict__ Ew)
{
    int v = blockIdx.x;
    int k = threadIdx.x;
    __shared__ float col[256];
    for (int i = 0; i < 4; ++i) col[i * 64 + k] = pw[(size_t)(i * 64 + k) * VV + v];
    __syncthreads();
    int s0 = w2s[v * SPWW];
    const float* hr = hpre + (size_t)(s0 + k) * HH;
    float acc = 0.f;
    #pragma unroll 4
    for (int h = 0; h < HH; ++h) acc += hr[h] * col[h];
    Ew[v * 64 + k] = acc + pb[v];
}

// ---------------- class word-lists ----------------
__global__ void fhmm_init_counts_kernel(int* counts, int* cursor) {
    int i = threadIdx.x;
    if (i < NCC) { counts[i] = 0; cursor[i] = 0; }
}
__global__ void fhmm_hist_kernel(const int* __restrict__ w2s, int* counts) {
    int v = blockIdx.x * 256 + threadIdx.x;
    if (v < VV) atomicAdd(&counts[w2s[v * SPWW] >> 6], 1);
}
__global__ void fhmm_offsets_kernel(const int* counts, int* offsets) {
    if (threadIdx.x == 0) {
        int acc = 0;
        for (int c = 0; c < NCC; ++c) { offsets[c] = acc; acc += counts[c]; }
        offsets[NCC] = acc;
    }
}
__global__ void fhmm_scatter_kernel(const int* __restrict__ w2s, const int* offsets,
                                    int* cursor, int* wlist) {
    int v = blockIdx.x * 256 + threadIdx.x;
    if (v < VV) {
        int c = w2s[v * SPWW] >> 6;
        int pos = atomicAdd(&cursor[c], 1);
        wlist[offsets[c] + pos] = v;
    }
}

// ---------------- per-state emission lse ----------------
__global__ __launch_bounds__(64) void fhmm_lse_em_kernel(
    const float* __restrict__ Ew, const int* __restrict__ wlist,
    const int* __restrict__ counts, const int* __restrict__ offsets,
    float* __restrict__ lse_em)
{
    int c = blockIdx.x, k = threadIdx.x;
    int cnt = counts[c], off = offsets[c];
    float m = -1e30f;
    for (int i = 0; i < cnt; ++i) m = fmaxf(m, Ew[wlist[off + i] * 64 + k]);
    float s = 0.f;
    for (int i = 0; i < cnt; ++i) s += expf(Ew[wlist[off + i] * 64 + k] - m);
    lse_em[c * 64 + k] = (cnt > 0) ? (m + logf(s)) : -1e30f;
}

// ---------------- obs[b,t,k] ----------------
__global__ __launch_bounds__(64) void fhmm_obs_kernel(
    const float* __restrict__ Ew, const float* __restrict__ lse_em,
    const int* __restrict__ text, const int* __restrict__ w2s,
    float* __restrict__ obs)
{
    int i = blockIdx.x;      // b*T + t
    int k = threadIdx.x;
    int v = text[i];
    int s = w2s[v * SPWW + k];
    obs[i * 64 + k] = Ew[v * 64 + k] - lse_em[s];
}

// ---------------- forward scan ----------------
__global__ __launch_bounds__(256) void fhmm_scan_kernel(
    const int* __restrict__ text, const int* __restrict__ w2s,
    const float* __restrict__ startv, const float* __restrict__ lse_trans,
    const float* __restrict__ pots, const float* __restrict__ obs,
    float* __restrict__ out)
{
    int b = blockIdx.x;
    int j = threadIdx.x & 63;
    int w = threadIdx.x >> 6;
    __shared__ float al[64];
    __shared__ float alpha_s[64];
    __shared__ float pm[4][64], ps[4][64];

    if (w == 0) {
        int v0 = text[b * TTT];
        int s = w2s[v0 * SPWW + j];
        alpha_s[j] = startv[s] + obs[(b * TTT) * 64 + j];
    }
    __syncthreads();

    for (int t = 1; t < TTT; ++t) {
        if (w == 0) {
            int vp = text[b * TTT + t - 1];
            int srow = w2s[vp * SPWW];
            al[j] = alpha_s[j] - lse_trans[srow + j];
        }
        __syncthreads();
        const float* pb = pots + (size_t)(b * (TTT - 1) + (t - 1)) * 4096;
        float pv[16];
        float m = -1e30f;
        #pragma unroll
        for (int ii = 0; ii < 16; ++ii) {
            int i = w * 16 + ii;
            pv[ii] = al[i] + pb[i * 64 + j];
            m = fmaxf(m, pv[ii]);
        }
        float ssum = 0.f;
        #pragma unroll
        for (int ii = 0; ii < 16; ++ii) ssum += expf(pv[ii] - m);
        pm[w][j] = m; ps[w][j] = ssum;
        __syncthreads();
        if (w == 0) {
            float M = pm[0][j], S = ps[0][j];
            #pragma unroll
            for (int q = 1; q < 4; ++q) {
                float m2 = pm[q][j], s2 = ps[q][j];
                float Mn = fmaxf(M, m2);
                S = S * expf(M - Mn) + s2 * expf(m2 - Mn);
                M = Mn;
            }
            alpha_s[j] = M + logf(S) + obs[(b * TTT + t) * 64 + j];
        }
        __syncthreads();
    }

    if (w == 0) {
        float a = alpha_s[j];
        float m = a;
        #pragma unroll
        for (int d = 32; d; d >>= 1) m = fmaxf(m, __shfl_xor(m, d));
        float s = expf(a - m);
        #pragma unroll
        for (int d = 32; d; d >>= 1) s += __shfl_xor(s, d);
        if (j == 0) out[b] = m + logf(s);
    }
}

extern "C" void kernel_launch(void* const* d_in, const int* in_sizes, int n_in,
                              void* d_out, int out_size, void* d_ws, size_t ws_size,
                              hipStream_t stream) {
    const int* text        = (const int*)d_in[0];
    const int* w2s         = (const int*)d_in[1];
    const float* se1_start = (const float*)d_in[2];
    const float* se2_start = (const float*)d_in[3];
    const float* start_w1  = (const float*)d_in[4];
    const float* start_b1  = (const float*)d_in[5];
    const float* start_w2  = (const float*)d_in[6];
    const float* start_b2  = (const float*)d_in[7];
    const float* start_pw  = (const float*)d_in[8];
    const float* start_pb  = (const float*)d_in[9];
    const float* se1_state = (const float*)d_in[10];
    const float* se2_state = (const float*)d_in[11];
    const float* se1_next  = (const float*)d_in[12];
    const float* se2_next  = (const float*)d_in[13];
    const float* trans_w1  = (const float*)d_in[14];
    const float* trans_b1  = (const float*)d_in[15];
    const float* trans_w2  = (const float*)d_in[16];
    const float* trans_b2  = (const float*)d_in[17];
    const float* se1_pre   = (const float*)d_in[18];
    const float* se2_pre   = (const float*)d_in[19];
    const float* term_w1   = (const float*)d_in[20];
    const float* term_b1   = (const float*)d_in[21];
    const float* term_w2   = (const float*)d_in[22];
    const float* term_b2   = (const float*)d_in[23];
    const float* term_pw   = (const float*)d_in[24];
    const float* term_pb   = (const float*)d_in[25];
    float* out = (float*)d_out;

    char* wp = (char*)d_ws;
    auto alloc = [&](size_t bytes) {
        char* p = wp;
        wp += (bytes + 255) & ~(size_t)255;
        return (void*)p;
    };
    float* h_state   = (float*)alloc((size_t)CST * HH * 4);
    float* h_pre     = (float*)alloc((size_t)CST * HH * 4);
    float* next_emb  = (float*)alloc((size_t)CST * HH * 4);
    float* tmp_h     = (float*)alloc((size_t)CST * HH * 4);
    float* startv    = (float*)alloc(CST * 4);
    float* lse_trans = (float*)alloc(CST * 4);
    float* lse_em    = (float*)alloc(CST * 4);
    float* Ew        = (float*)alloc((size_t)VV * 64 * 4);
    int* counts      = (int*)alloc(NCC * 4);
    int* offsets     = (int*)alloc((NCC + 4) * 4);
    int* cursor      = (int*)alloc(NCC * 4);
    int* wlist       = (int*)alloc(VV * 4);
    float* obs       = (float*)alloc((size_t)BBB * TTT * 64 * 4);
    float* pots      = (float*)alloc((size_t)BBB * (TTT - 1) * 4096 * 4);

    dim3 mmGrid(128, 4);

    // start head (uses h_pre as temp for h_start; overwritten later)
    hipLaunchKernelGGL(fhmm_mlp_kernel, mmGrid, 256, 0, stream,
                       (const float*)nullptr, se1_start, se2_start, start_w1, start_b1,
                       (const float*)nullptr, (const float*)nullptr, tmp_h, 1, 0);
    hipLaunchKernelGGL(fhmm_mlp_kernel, mmGrid, 256, 0, stream,
                       tmp_h, (const float*)nullptr, (const float*)nullptr, start_w2, start_b2,
                       se1_start, se2_start, h_pre, 0, 1);
    hipLaunchKernelGGL(fhmm_dotpw_kernel, dim3(2048), 256, 0, stream,
                       h_pre, start_pw, start_pb, startv);
    hipLaunchKernelGGL(fhmm_lsm_vec_kernel, dim3(1), 1024, 0, stream, startv);

    // state head -> h_state
    hipLaunchKernelGGL(fhmm_mlp_kernel, mmGrid, 256, 0, stream,
                       (const float*)nullptr, se1_state, se2_state, trans_w1, trans_b1,
                       (const float*)nullptr, (const float*)nullptr, tmp_h, 1, 0);
    hipLaunchKernelGGL(fhmm_mlp_kernel, mmGrid, 256, 0, stream,
                       tmp_h, (const float*)nullptr, (const float*)nullptr, trans_w2, trans_b2,
                       se1_state, se2_state, h_state, 0, 1);

    // pre head -> h_pre
    hipLaunchKernelGGL(fhmm_mlp_kernel, mmGrid, 256, 0, stream,
                       (const float*)nullptr, se1_pre, se2_pre, term_w1, term_b1,
                       (const float*)nullptr, (const float*)nullptr, tmp_h, 1, 0);
    hipLaunchKernelGGL(fhmm_mlp_kernel, mmGrid, 256, 0, stream,
                       tmp_h, (const float*)nullptr, (const float*)nullptr, term_w2, term_b2,
                       se1_pre, se2_pre, h_pre, 0, 1);

    // next_emb
    hipLaunchKernelGGL(fhmm_emb_kernel, dim3(8192), 256, 0, stream,
                       se1_next, se2_next, next_emb);

    // transition row-lse (streaming over all 8192 cols)
    hipLaunchKernelGGL(fhmm_trans_lse_kernel, dim3(256), 256, 0, stream,
                       h_state, next_emb, lse_trans);

    // per-(b,t) 64x64 logit blocks
    hipLaunchKernelGGL(fhmm_pots_kernel, dim3(BBB * (TTT - 1)), 256, 0, stream,
                       h_state, next_emb, text, w2s, pots);

    // emission
    hipLaunchKernelGGL(fhmm_ew_kernel, dim3(VV), 64, 0, stream,
                       h_pre, term_pw, term_pb, w2s, Ew);
    hipLaunchKernelGGL(fhmm_init_counts_kernel, dim3(1), 128, 0, stream, counts, cursor);
    hipLaunchKernelGGL(fhmm_hist_kernel, dim3(40), 256, 0, stream, w2s, counts);
    hipLaunchKernelGGL(fhmm_offsets_kernel, dim3(1), 64, 0, stream, counts, offsets);
    hipLaunchKernelGGL(fhmm_scatter_kernel, dim3(40), 256, 0, stream, w2s, offsets, cursor, wlist);
    hipLaunchKernelGGL(fhmm_lse_em_kernel, dim3(NCC), 64, 0, stream,
                       Ew, wlist, counts, offsets, lse_em);
    hipLaunchKernelGGL(fhmm_obs_kernel, dim3(BBB * TTT), 64, 0, stream,
                       Ew, lse_em, text, w2s, obs);

    // forward scan + final logsumexp
    hipLaunchKernelGGL(fhmm_scan_kernel, dim3(BBB), 256, 0, stream,
                       text, w2s, startv, lse_trans, pots, obs, out);
}

// Round 2
// 1372.793 us; speedup vs baseline: 3.3975x; 3.3975x over previous
//
#include <hip/hip_runtime.h>
#include <hip/hip_bf16.h>
#include <math.h>

#define HH 256
#define NCC 128
#define SPWW 64
#define CST 8192
#define VV 10000
#define BBB 16
#define TTT 256

typedef __attribute__((ext_vector_type(8))) short short8;
typedef __attribute__((ext_vector_type(4))) float f32x4;

// ---------------- embeddings (bf16 out) ----------------
__global__ __launch_bounds__(256) void fhmm_emb_bf16_kernel(
    const float* __restrict__ e1, const float* __restrict__ e2,
    __hip_bfloat16* __restrict__ out)
{
    int idx = blockIdx.x * 256 + threadIdx.x;   // over 8192*256
    int s = idx >> 8, h = idx & 255;
    out[idx] = __float2bfloat16(e1[(s >> 6) * HH + h] + e2[(s & 63) * HH + h]);
}

// ---------------- residual MLP matmul (M=8192, K=N=256) ----------------
__global__ __launch_bounds__(256) void fhmm_mlp_kernel(
    const float* __restrict__ X,
    const float* __restrict__ se1x, const float* __restrict__ se2x,
    const float* __restrict__ W, const float* __restrict__ bias,
    const float* __restrict__ se1r, const float* __restrict__ se2r,
    float* __restrict__ Y, __hip_bfloat16* __restrict__ Ybf,
    int emb_x, int add_res)
{
    int m0 = blockIdx.x * 64;
    int n0 = blockIdx.y * 64;
    int tid = threadIdx.x;
    __shared__ float Xs[64][65];
    __shared__ float Ws[64][65];
    int ty = tid >> 4, tx = tid & 15;
    float acc[4][4] = {};
    for (int kt = 0; kt < 4; ++kt) {
        __syncthreads();
        for (int i = 0; i < 16; ++i) {
            int idx = tid + i * 256;
            int rl = idx >> 6, cl = idx & 63;
            int gk = kt * 64 + cl;
            int gm = m0 + rl;
            float xv;
            if (emb_x) xv = se1x[(gm >> 6) * HH + gk] + se2x[(gm & 63) * HH + gk];
            else       xv = X[gm * HH + gk];
            Xs[rl][cl] = xv;
            Ws[rl][cl] = W[(kt * 64 + rl) * HH + n0 + cl];
        }
        __syncthreads();
        #pragma unroll
        for (int kk = 0; kk < 64; ++kk) {
            float av[4], bv[4];
            #pragma unroll
            for (int i = 0; i < 4; ++i) av[i] = Xs[ty * 4 + i][kk];
            #pragma unroll
            for (int j = 0; j < 4; ++j) bv[j] = Ws[kk][tx * 4 + j];
            #pragma unroll
            for (int i = 0; i < 4; ++i)
                #pragma unroll
                for (int j = 0; j < 4; ++j)
                    acc[i][j] += av[i] * bv[j];
        }
    }
    #pragma unroll
    for (int i = 0; i < 4; ++i) {
        int gm = m0 + ty * 4 + i;
        #pragma unroll
        for (int j = 0; j < 4; ++j) {
            int gn = n0 + tx * 4 + j;
            float yv = acc[i][j] + bias[gn];
            yv = fmaxf(yv, 0.f);
            if (add_res) yv += se1r[(gm >> 6) * HH + gn] + se2r[(gm & 63) * HH + gn];
            Y[gm * HH + gn] = yv;
            if (Ybf) Ybf[gm * HH + gn] = __float2bfloat16(yv);
        }
    }
}

// ---------------- start head: dot with pw ----------------
__global__ __launch_bounds__(256) void fhmm_dotpw_kernel(
    const float* __restrict__ hstart, const float* __restrict__ pw,
    const float* __restrict__ pbp, float* __restrict__ p)
{
    int wv = threadIdx.x >> 6;
    int lane = threadIdx.x & 63;
    int s = blockIdx.x * 4 + wv;
    const float* hr = hstart + (size_t)s * HH;
    float acc = 0.f;
    #pragma unroll
    for (int i = 0; i < 4; ++i) acc += hr[i * 64 + lane] * pw[i * 64 + lane];
    #pragma unroll
    for (int d = 32; d; d >>= 1) acc += __shfl_xor(acc, d);
    if (lane == 0) p[s] = acc + pbp[0];
}

// ---------------- in-place log_softmax over a length-8192 vector ----------------
__global__ __launch_bounds__(1024) void fhmm_lsm_vec_kernel(float* __restrict__ p)
{
    __shared__ float red[64];
    int tid = threadIdx.x;
    float m = -1e30f;
    for (int i = tid; i < CST; i += 1024) m = fmaxf(m, p[i]);
    #pragma unroll
    for (int d = 32; d; d >>= 1) m = fmaxf(m, __shfl_xor(m, d));
    if ((tid & 63) == 0) red[tid >> 6] = m;
    __syncthreads();
    if (tid == 0) {
        float mm = red[0];
        for (int q = 1; q < 16; ++q) mm = fmaxf(mm, red[q]);
        red[32] = mm;
    }
    __syncthreads();
    float M = red[32];
    float s = 0.f;
    for (int i = tid; i < CST; i += 1024) s += expf(p[i] - M);
    #pragma unroll
    for (int d = 32; d; d >>= 1) s += __shfl_xor(s, d);
    if ((tid & 63) == 0) red[tid >> 6] = s;
    __syncthreads();
    if (tid == 0) {
        float ss = 0.f;
        for (int q = 0; q < 16; ++q) ss += red[q];
        red[33] = ss;
    }
    __syncthreads();
    float lse = M + logf(red[33]);
    for (int i = tid; i < CST; i += 1024) p[i] -= lse;
}

// ---------------- transition row-lse via MFMA (streaming over 8192 cols) ----------------
// C[r][c] = sum_k A[r][k]*B[c][k]; swapped mfma(Bfrag, Afrag) so each lane's
// acc holds 4 cols of the SAME row -> lane-local online lse.
__global__ __launch_bounds__(256) void fhmm_trans_lse_mfma(
    const __hip_bfloat16* __restrict__ Abf,   // h_state bf16 [8192][256]
    const __hip_bfloat16* __restrict__ Bbf,   // next_emb bf16 [8192][256]
    float* __restrict__ lse)
{
    __shared__ char bs[2][32768];
    __shared__ float cmb[4][32], csb[4][32];
    int tid = threadIdx.x;
    int w = tid >> 6, lane = tid & 63;
    int lr = lane & 15, lg = lane >> 4;
    int r0 = blockIdx.x * 32;

    // A fragments (used as MFMA B-operand), registers for whole kernel:
    // 2 row-tiles x 8 k-steps; lane: row r0+rm*16+lr, k = ks*32+lg*8..+7
    short8 afr[2][8];
    #pragma unroll
    for (int rm = 0; rm < 2; ++rm)
        #pragma unroll
        for (int ks = 0; ks < 8; ++ks)
            afr[rm][ks] = *reinterpret_cast<const short8*>(
                Abf + (size_t)(r0 + rm * 16 + lr) * HH + ks * 32 + lg * 8);

    // staging offsets: chunk c = i*256+tid of 16B; row=c>>5, slot=c&31
    int soff[8], doff[8];
    #pragma unroll
    for (int i = 0; i < 8; ++i) {
        int c = i * 256 + tid;
        int row = c >> 5, t = c & 31;
        soff[i] = c * 16;
        doff[i] = row * 512 + ((t ^ (row & 7)) << 4);
    }
    const char* Bbytes = reinterpret_cast<const char*>(Bbf);
    #pragma unroll
    for (int i = 0; i < 8; ++i)
        *reinterpret_cast<uint4*>(&bs[0][doff[i]]) =
            *reinterpret_cast<const uint4*>(Bbytes + soff[i]);
    __syncthreads();

    float m0 = -1e30f, s0 = 0.f, m1 = -1e30f, s1 = 0.f;
    int brow = w * 16 + lr;          // this lane's C-col row within B-tile
    int bbase = brow * 512;
    int bswz = (brow & 7) << 4;

    for (int ct = 0; ct < 128; ++ct) {
        uint4 stg[8];
        if (ct < 127) {
            const char* src = Bbytes + (size_t)(ct + 1) * 32768;
            #pragma unroll
            for (int i = 0; i < 8; ++i)
                stg[i] = *reinterpret_cast<const uint4*>(src + soff[i]);
        }
        const char* bsrc = bs[ct & 1];
        f32x4 acc0 = {0.f, 0.f, 0.f, 0.f};
        f32x4 acc1 = {0.f, 0.f, 0.f, 0.f};
        #pragma unroll
        for (int ks = 0; ks < 8; ++ks) {
            short8 bf = *reinterpret_cast<const short8*>(
                bsrc + bbase + ((((ks * 4 + lg)) << 4) ^ bswz));
            acc0 = __builtin_amdgcn_mfma_f32_16x16x32_bf16(bf, afr[0][ks], acc0, 0, 0, 0);
            acc1 = __builtin_amdgcn_mfma_f32_16x16x32_bf16(bf, afr[1][ks], acc1, 0, 0, 0);
        }
        // online lse update: acc0 -> local row lr, acc1 -> local row 16+lr
        {
            float lm = fmaxf(fmaxf(acc0[0], acc0[1]), fmaxf(acc0[2], acc0[3]));
            float mn = fmaxf(m0, lm);
            s0 = s0 * __expf(m0 - mn)
               + __expf(acc0[0] - mn) + __expf(acc0[1] - mn)
               + __expf(acc0[2] - mn) + __expf(acc0[3] - mn);
            m0 = mn;
        }
        {
            float lm = fmaxf(fmaxf(acc1[0], acc1[1]), fmaxf(acc1[2], acc1[3]));
            float mn = fmaxf(m1, lm);
            s1 = s1 * __expf(m1 - mn)
               + __expf(acc1[0] - mn) + __expf(acc1[1] - mn)
               + __expf(acc1[2] - mn) + __expf(acc1[3] - mn);
            m1 = mn;
        }
        if (ct < 127) {
            char* dstb = bs[(ct + 1) & 1];
            #pragma unroll
            for (int i = 0; i < 8; ++i)
                *reinterpret_cast<uint4*>(dstb + doff[i]) = stg[i];
        }
        __syncthreads();
    }

    // combine across lane groups (bits 4,5 of lane): cols partition
    #pragma unroll
    for (int d = 16; d < 64; d <<= 1) {
        float m2 = __shfl_xor(m0, d), sx = __shfl_xor(s0, d);
        float mn = fmaxf(m0, m2);
        s0 = s0 * __expf(m0 - mn) + sx * __expf(m2 - mn); m0 = mn;
        m2 = __shfl_xor(m1, d); sx = __shfl_xor(s1, d);
        mn = fmaxf(m1, m2);
        s1 = s1 * __expf(m1 - mn) + sx * __expf(m2 - mn); m1 = mn;
    }
    if (lane < 16) {
        cmb[w][lane] = m0;      csb[w][lane] = s0;
        cmb[w][lane + 16] = m1; csb[w][lane + 16] = s1;
    }
    __syncthreads();
    if (tid < 32) {
        float M = cmb[0][tid], S = csb[0][tid];
        #pragma unroll
        for (int q = 1; q < 4; ++q) {
            float m2 = cmb[q][tid], sx = csb[q][tid];
            float mn = fmaxf(M, m2);
            S = S * __expf(M - mn) + sx * __expf(m2 - mn); M = mn;
        }
        lse[r0 + tid] = M + logf(S);
    }
}

// ---------------- per-(b,t) 64x64 transition-logit blocks via MFMA ----------------
__global__ __launch_bounds__(256) void fhmm_pots_mfma(
    const __hip_bfloat16* __restrict__ Abf, const __hip_bfloat16* __restrict__ Bbf,
    const int* __restrict__ text, const int* __restrict__ w2s,
    float* __restrict__ pots)
{
    int blk = blockIdx.x;              // b*255 + t
    int b = blk / (TTT - 1), t = blk % (TTT - 1);
    int sr = w2s[text[b * TTT + t] * SPWW];
    int sc = w2s[text[b * TTT + t + 1] * SPWW];
    __shared__ char As_[32768];
    __shared__ char Bs_[32768];
    int tid = threadIdx.x;
    int w = tid >> 6, lane = tid & 63;
    int lr = lane & 15, lg = lane >> 4;

    const char* Asrc = reinterpret_cast<const char*>(Abf + (size_t)sr * HH);
    const char* Bsrc = reinterpret_cast<const char*>(Bbf + (size_t)sc * HH);
    #pragma unroll
    for (int i = 0; i < 8; ++i) {
        int c = i * 256 + tid;
        int row = c >> 5, tt = c & 31;
        int dst = row * 512 + ((tt ^ (row & 7)) << 4);
        *reinterpret_cast<uint4*>(&As_[dst]) = *reinterpret_cast<const uint4*>(Asrc + c * 16);
        *reinterpret_cast<uint4*>(&Bs_[dst]) = *reinterpret_cast<const uint4*>(Bsrc + c * 16);
    }
    __syncthreads();

    // B-tile fragments for this wave's 16-col slice (as MFMA A-operand)
    short8 bfr[8];
    int brow = w * 16 + lr;
    int bbase = brow * 512;
    int bswz = (brow & 7) << 4;
    #pragma unroll
    for (int ks = 0; ks < 8; ++ks)
        bfr[ks] = *reinterpret_cast<const short8*>(
            Bs_ + bbase + (((ks * 4 + lg) << 4) ^ bswz));

    f32x4 acc[4];
    #pragma unroll
    for (int rm = 0; rm < 4; ++rm) acc[rm] = (f32x4){0.f, 0.f, 0.f, 0.f};

    #pragma unroll
    for (int rm = 0; rm < 4; ++rm) {
        int arow = rm * 16 + lr;
        int abase = arow * 512;
        int aswz = (arow & 7) << 4;
        #pragma unroll
        for (int ks = 0; ks < 8; ++ks) {
            short8 af = *reinterpret_cast<const short8*>(
                As_ + abase + (((ks * 4 + lg) << 4) ^ aswz));
            acc[rm] = __builtin_amdgcn_mfma_f32_16x16x32_bf16(bfr[ks], af, acc[rm], 0, 0, 0);
        }
    }
    // lane holds row rm*16+lr, cols w*16+lg*4..+3 (contiguous float4)
    float* op = pots + (size_t)blk * 4096;
    #pragma unroll
    for (int rm = 0; rm < 4; ++rm)
        *reinterpret_cast<f32x4*>(op + (size_t)(rm * 16 + lr) * 64 + w * 16 + lg * 4) = acc[rm];
}

// ---------------- emission logits per (word, own 64 states) ----------------
__global__ __launch_bounds__(64) void fhmm_ew_kernel(
    const float* __restrict__ hpre, const float* __restrict__ pw,
    const float* __restrict__ pb, const int* __restrict__ w2s,
    float* __restrict__ Ew)
{
    int v = blockIdx.x;
    int k = threadIdx.x;
    __shared__ float col[256];
    for (int i = 0; i < 4; ++i) col[i * 64 + k] = pw[(size_t)(i * 64 + k) * VV + v];
    __syncthreads();
    int s0 = w2s[v * SPWW];
    const float* hr = hpre + (size_t)(s0 + k) * HH;
    float acc = 0.f;
    #pragma unroll 4
    for (int h = 0; h < HH; ++h) acc += hr[h] * col[h];
    Ew[v * 64 + k] = acc + pb[v];
}

// ---------------- class word-lists ----------------
__global__ void fhmm_init_counts_kernel(int* counts, int* cursor) {
    int i = threadIdx.x;
    if (i < NCC) { counts[i] = 0; cursor[i] = 0; }
}
__global__ void fhmm_hist_kernel(const int* __restrict__ w2s, int* counts) {
    int v = blockIdx.x * 256 + threadIdx.x;
    if (v < VV) atomicAdd(&counts[w2s[v * SPWW] >> 6], 1);
}
__global__ void fhmm_offsets_kernel(const int* counts, int* offsets) {
    if (threadIdx.x == 0) {
        int acc = 0;
        for (int c = 0; c < NCC; ++c) { offsets[c] = acc; acc += counts[c]; }
        offsets[NCC] = acc;
    }
}
__global__ void fhmm_scatter_kernel(const int* __restrict__ w2s, const int* offsets,
                                    int* cursor, int* wlist) {
    int v = blockIdx.x * 256 + threadIdx.x;
    if (v < VV) {
        int c = w2s[v * SPWW] >> 6;
        int pos = atomicAdd(&cursor[c], 1);
        wlist[offsets[c] + pos] = v;
    }
}

// ---------------- per-state emission lse ----------------
__global__ __launch_bounds__(64) void fhmm_lse_em_kernel(
    const float* __restrict__ Ew, const int* __restrict__ wlist,
    const int* __restrict__ counts, const int* __restrict__ offsets,
    float* __restrict__ lse_em)
{
    int c = blockIdx.x, k = threadIdx.x;
    int cnt = counts[c], off = offsets[c];
    float m = -1e30f;
    for (int i = 0; i < cnt; ++i) m = fmaxf(m, Ew[wlist[off + i] * 64 + k]);
    float s = 0.f;
    for (int i = 0; i < cnt; ++i) s += expf(Ew[wlist[off + i] * 64 + k] - m);
    lse_em[c * 64 + k] = (cnt > 0) ? (m + logf(s)) : -1e30f;
}

// ---------------- obs[b,t,k] ----------------
__global__ __launch_bounds__(64) void fhmm_obs_kernel(
    const float* __restrict__ Ew, const float* __restrict__ lse_em,
    const int* __restrict__ text, const int* __restrict__ w2s,
    float* __restrict__ obs)
{
    int i = blockIdx.x;      // b*T + t
    int k = threadIdx.x;
    int v = text[i];
    int s = w2s[v * SPWW + k];
    obs[i * 64 + k] = Ew[v * 64 + k] - lse_em[s];
}

// ---------------- forward scan ----------------
__global__ __launch_bounds__(256) void fhmm_scan_kernel(
    const int* __restrict__ text, const int* __restrict__ w2s,
    const float* __restrict__ startv, const float* __restrict__ lse_trans,
    const float* __restrict__ pots, const float* __restrict__ obs,
    float* __restrict__ out)
{
    int b = blockIdx.x;
    int j = threadIdx.x & 63;
    int w = threadIdx.x >> 6;
    __shared__ float al[64];
    __shared__ float alpha_s[64];
    __shared__ float pm[4][64], ps[4][64];

    if (w == 0) {
        int v0 = text[b * TTT];
        int s = w2s[v0 * SPWW + j];
        alpha_s[j] = startv[s] + obs[(b * TTT) * 64 + j];
    }
    __syncthreads();

    for (int t = 1; t < TTT; ++t) {
        if (w == 0) {
            int vp = text[b * TTT + t - 1];
            int srow = w2s[vp * SPWW];
            al[j] = alpha_s[j] - lse_trans[srow + j];
        }
        __syncthreads();
        const float* pb = pots + (size_t)(b * (TTT - 1) + (t - 1)) * 4096;
        float pv[16];
        float m = -1e30f;
        #pragma unroll
        for (int ii = 0; ii < 16; ++ii) {
            int i = w * 16 + ii;
            pv[ii] = al[i] + pb[i * 64 + j];
            m = fmaxf(m, pv[ii]);
        }
        float ssum = 0.f;
        #pragma unroll
        for (int ii = 0; ii < 16; ++ii) ssum += expf(pv[ii] - m);
        pm[w][j] = m; ps[w][j] = ssum;
        __syncthreads();
        if (w == 0) {
            float M = pm[0][j], S = ps[0][j];
            #pragma unroll
            for (int q = 1; q < 4; ++q) {
                float m2 = pm[q][j], s2 = ps[q][j];
                float Mn = fmaxf(M, m2);
                S = S * expf(M - Mn) + s2 * expf(m2 - Mn);
                M = Mn;
            }
            alpha_s[j] = M + logf(S) + obs[(b * TTT + t) * 64 + j];
        }
        __syncthreads();
    }

    if (w == 0) {
        float a = alpha_s[j];
        float m = a;
        #pragma unroll
        for (int d = 32; d; d >>= 1) m = fmaxf(m, __shfl_xor(m, d));
        float s = expf(a - m);
        #pragma unroll
        for (int d = 32; d; d >>= 1) s += __shfl_xor(s, d);
        if (j == 0) out[b] = m + logf(s);
    }
}

extern "C" void kernel_launch(void* const* d_in, const int* in_sizes, int n_in,
                              void* d_out, int out_size, void* d_ws, size_t ws_size,
                              hipStream_t stream) {
    const int* text        = (const int*)d_in[0];
    const int* w2s         = (const int*)d_in[1];
    const float* se1_start = (const float*)d_in[2];
    const float* se2_start = (const float*)d_in[3];
    const float* start_w1  = (const float*)d_in[4];
    const float* start_b1  = (const float*)d_in[5];
    const float* start_w2  = (const float*)d_in[6];
    const float* start_b2  = (const float*)d_in[7];
    const float* start_pw  = (const float*)d_in[8];
    const float* start_pb  = (const float*)d_in[9];
    const float* se1_state = (const float*)d_in[10];
    const float* se2_state = (const float*)d_in[11];
    const float* se1_next  = (const float*)d_in[12];
    const float* se2_next  = (const float*)d_in[13];
    const float* trans_w1  = (const float*)d_in[14];
    const float* trans_b1  = (const float*)d_in[15];
    const float* trans_w2  = (const float*)d_in[16];
    const float* trans_b2  = (const float*)d_in[17];
    const float* se1_pre   = (const float*)d_in[18];
    const float* se2_pre   = (const float*)d_in[19];
    const float* term_w1   = (const float*)d_in[20];
    const float* term_b1   = (const float*)d_in[21];
    const float* term_w2   = (const float*)d_in[22];
    const float* term_b2   = (const float*)d_in[23];
    const float* term_pw   = (const float*)d_in[24];
    const float* term_pb   = (const float*)d_in[25];
    float* out = (float*)d_out;

    char* wp = (char*)d_ws;
    auto alloc = [&](size_t bytes) {
        char* p = wp;
        wp += (bytes + 255) & ~(size_t)255;
        return (void*)p;
    };
    float* h_state   = (float*)alloc((size_t)CST * HH * 4);
    float* h_pre     = (float*)alloc((size_t)CST * HH * 4);
    float* tmp_h     = (float*)alloc((size_t)CST * HH * 4);
    __hip_bfloat16* h_state_bf = (__hip_bfloat16*)alloc((size_t)CST * HH * 2);
    __hip_bfloat16* next_emb_bf = (__hip_bfloat16*)alloc((size_t)CST * HH * 2);
    float* startv    = (float*)alloc(CST * 4);
    float* lse_trans = (float*)alloc(CST * 4);
    float* lse_em    = (float*)alloc(CST * 4);
    float* Ew        = (float*)alloc((size_t)VV * 64 * 4);
    int* counts      = (int*)alloc(NCC * 4);
    int* offsets     = (int*)alloc((NCC + 4) * 4);
    int* cursor      = (int*)alloc(NCC * 4);
    int* wlist       = (int*)alloc(VV * 4);
    float* obs       = (float*)alloc((size_t)BBB * TTT * 64 * 4);
    float* pots      = (float*)alloc((size_t)BBB * (TTT - 1) * 4096 * 4);

    dim3 mmGrid(128, 4);

    // start head (h_pre as temp for h_start; overwritten later)
    hipLaunchKernelGGL(fhmm_mlp_kernel, mmGrid, 256, 0, stream,
                       (const float*)nullptr, se1_start, se2_start, start_w1, start_b1,
                       (const float*)nullptr, (const float*)nullptr, tmp_h,
                       (__hip_bfloat16*)nullptr, 1, 0);
    hipLaunchKernelGGL(fhmm_mlp_kernel, mmGrid, 256, 0, stream,
                       tmp_h, (const float*)nullptr, (const float*)nullptr, start_w2, start_b2,
                       se1_start, se2_start, h_pre, (__hip_bfloat16*)nullptr, 0, 1);
    hipLaunchKernelGGL(fhmm_dotpw_kernel, dim3(2048), 256, 0, stream,
                       h_pre, start_pw, start_pb, startv);
    hipLaunchKernelGGL(fhmm_lsm_vec_kernel, dim3(1), 1024, 0, stream, startv);

    // state head -> h_state (+ bf16 copy)
    hipLaunchKernelGGL(fhmm_mlp_kernel, mmGrid, 256, 0, stream,
                       (const float*)nullptr, se1_state, se2_state, trans_w1, trans_b1,
                       (const float*)nullptr, (const float*)nullptr, tmp_h,
                       (__hip_bfloat16*)nullptr, 1, 0);
    hipLaunchKernelGGL(fhmm_mlp_kernel, mmGrid, 256, 0, stream,
                       tmp_h, (const float*)nullptr, (const float*)nullptr, trans_w2, trans_b2,
                       se1_state, se2_state, h_state, h_state_bf, 0, 1);

    // pre head -> h_pre
    hipLaunchKernelGGL(fhmm_mlp_kernel, mmGrid, 256, 0, stream,
                       (const float*)nullptr, se1_pre, se2_pre, term_w1, term_b1,
                       (const float*)nullptr, (const float*)nullptr, tmp_h,
                       (__hip_bfloat16*)nullptr, 1, 0);
    hipLaunchKernelGGL(fhmm_mlp_kernel, mmGrid, 256, 0, stream,
                       tmp_h, (const float*)nullptr, (const float*)nullptr, term_w2, term_b2,
                       se1_pre, se2_pre, h_pre, (__hip_bfloat16*)nullptr, 0, 1);

    // next_emb (bf16)
    hipLaunchKernelGGL(fhmm_emb_bf16_kernel, dim3(8192), 256, 0, stream,
                       se1_next, se2_next, next_emb_bf);

    // transition row-lse via MFMA
    hipLaunchKernelGGL(fhmm_trans_lse_mfma, dim3(256), 256, 0, stream,
                       h_state_bf, next_emb_bf, lse_trans);

    // per-(b,t) 64x64 logit blocks via MFMA
    hipLaunchKernelGGL(fhmm_pots_mfma, dim3(BBB * (TTT - 1)), 256, 0, stream,
                       h_state_bf, next_emb_bf, text, w2s, pots);

    // emission
    hipLaunchKernelGGL(fhmm_ew_kernel, dim3(VV), 64, 0, stream,
                       h_pre, term_pw, term_pb, w2s, Ew);
    hipLaunchKernelGGL(fhmm_init_counts_kernel, dim3(1), 128, 0, stream, counts, cursor);
    hipLaunchKernelGGL(fhmm_hist_kernel, dim3(40), 256, 0, stream, w2s, counts);
    hipLaunchKernelGGL(fhmm_offsets_kernel, dim3(1), 64, 0, stream, counts, offsets);
    hipLaunchKernelGGL(fhmm_scatter_kernel, dim3(40), 256, 0, stream, w2s, offsets, cursor, wlist);
    hipLaunchKernelGGL(fhmm_lse_em_kernel, dim3(NCC), 64, 0, stream,
                       Ew, wlist, counts, offsets, lse_em);
    hipLaunchKernelGGL(fhmm_obs_kernel, dim3(BBB * TTT), 64, 0, stream,
                       Ew, lse_em, text, w2s, obs);

    // forward scan + final logsumexp
    hipLaunchKernelGGL(fhmm_scan_kernel, dim3(BBB), 256, 0, stream,
                       text, w2s, startv, lse_trans, pots, obs, out);
}

// Round 3
// 531.030 us; speedup vs baseline: 8.7830x; 2.5852x over previous
//
#include <hip/hip_runtime.h>
#include <hip/hip_bf16.h>
#include <math.h>

#define HH 256
#define NCC 128
#define SPWW 64
#define CST 8192
#define VV 10000
#define BBB 16
#define TTT 256

typedef __attribute__((ext_vector_type(8))) short short8;
typedef __attribute__((ext_vector_type(4))) float f32x4;
typedef unsigned short u16;

__device__ inline float bf2f(u16 u) {
    union { unsigned int i; float f; } v; v.i = ((unsigned int)u) << 16; return v.f;
}
__device__ inline u16 f2bf(float f) {
    __hip_bfloat16 h = __float2bfloat16(f);
    return *reinterpret_cast<u16*>(&h);
}

// ---------------- embeddings (bf16 out) ----------------
__global__ __launch_bounds__(256) void fhmm_emb_bf16_kernel(
    const float* __restrict__ e1, const float* __restrict__ e2,
    u16* __restrict__ out)
{
    int idx = blockIdx.x * 256 + threadIdx.x;   // over 8192*256
    int s = idx >> 8, h = idx & 255;
    out[idx] = f2bf(e1[(s >> 6) * HH + h] + e2[(s & 63) * HH + h]);
}

// ---------------- weight transpose 256x256: Wt[n][k] = bf16(W[k][n]) ----------------
__global__ __launch_bounds__(256) void fhmm_wtrans_kernel(
    const float* __restrict__ W, u16* __restrict__ Wt)
{
    __shared__ float t[64][65];
    int k0 = blockIdx.x * 64, n0 = blockIdx.y * 64, tid = threadIdx.x;
    #pragma unroll
    for (int i = 0; i < 16; ++i) {
        int idx = tid + i * 256; int r = idx >> 6, c = idx & 63;
        t[r][c] = W[(k0 + r) * HH + n0 + c];
    }
    __syncthreads();
    #pragma unroll
    for (int i = 0; i < 16; ++i) {
        int idx = tid + i * 256; int r = idx >> 6, c = idx & 63;
        Wt[(n0 + r) * HH + k0 + c] = f2bf(t[c][r]);
    }
}

// ---------------- pw transpose: pwT[v][k] = bf16(pw[k][v]) ----------------
__global__ __launch_bounds__(256) void fhmm_pwtrans_kernel(
    const float* __restrict__ pw, u16* __restrict__ pwT)
{
    __shared__ float t[64][65];
    int v0 = blockIdx.x * 64, k0 = blockIdx.y * 64, tid = threadIdx.x;
    #pragma unroll
    for (int i = 0; i < 16; ++i) {
        int idx = tid + i * 256; int r = idx >> 6, c = idx & 63;   // r:k, c:v
        int v = v0 + c;
        t[r][c] = (v < VV) ? pw[(size_t)(k0 + r) * VV + v] : 0.f;
    }
    __syncthreads();
    #pragma unroll
    for (int i = 0; i < 16; ++i) {
        int idx = tid + i * 256; int r = idx >> 6, c = idx & 63;   // r:v, c:k
        int v = v0 + r;
        if (v < VV) pwT[(size_t)v * HH + k0 + c] = f2bf(t[c][r]);
    }
}

// ---------------- MFMA MLP layer: Y = relu(X@W + b) [+ res], all bf16 I/O ----------------
__global__ __launch_bounds__(256) void fhmm_mlp_mfma(
    const u16* __restrict__ Xbf, const u16* __restrict__ Wt,
    const float* __restrict__ bias, const u16* __restrict__ resbf,
    u16* __restrict__ Ybf)
{
    int m0 = blockIdx.x * 64, n0 = blockIdx.y * 64;
    __shared__ char Xs[32768];
    __shared__ char Ws[32768];
    int tid = threadIdx.x, w = tid >> 6, lane = tid & 63, lr = lane & 15, lg = lane >> 4;
    const char* xsrc = (const char*)(Xbf + (size_t)m0 * HH);
    const char* wsrc = (const char*)(Wt + (size_t)n0 * HH);
    #pragma unroll
    for (int i = 0; i < 8; ++i) {
        int cc = i * 256 + tid; int row = cc >> 5, tt = cc & 31;
        int dst = row * 512 + ((tt ^ (row & 7)) << 4);
        *(uint4*)&Xs[dst] = *(const uint4*)(xsrc + cc * 16);
        *(uint4*)&Ws[dst] = *(const uint4*)(wsrc + cc * 16);
    }
    __syncthreads();
    short8 bfr[8];
    int brow = w * 16 + lr, bb = brow * 512, bsw = (brow & 7) << 4;
    #pragma unroll
    for (int ks = 0; ks < 8; ++ks)
        bfr[ks] = *(const short8*)(Ws + bb + (((ks * 4 + lg) << 4) ^ bsw));
    int cb = w * 16 + lg * 4;
    f32x4 bv = *(const f32x4*)(bias + n0 + cb);
    #pragma unroll
    for (int rm = 0; rm < 4; ++rm) {
        f32x4 acc = {0.f, 0.f, 0.f, 0.f};
        int ar = rm * 16 + lr, ab = ar * 512, asw = (ar & 7) << 4;
        #pragma unroll
        for (int ks = 0; ks < 8; ++ks) {
            short8 af = *(const short8*)(Xs + ab + (((ks * 4 + lg) << 4) ^ asw));
            acc = __builtin_amdgcn_mfma_f32_16x16x32_bf16(bfr[ks], af, acc, 0, 0, 0);
        }
        int gm = m0 + rm * 16 + lr;
        ushort4 o;
        if (resbf) {
            const u16* rp = resbf + (size_t)gm * HH + n0 + cb;
            #pragma unroll
            for (int e = 0; e < 4; ++e)
                ((u16*)&o)[e] = f2bf(fmaxf(acc[e] + bv[e], 0.f) + bf2f(rp[e]));
        } else {
            #pragma unroll
            for (int e = 0; e < 4; ++e)
                ((u16*)&o)[e] = f2bf(fmaxf(acc[e] + bv[e], 0.f));
        }
        *(ushort4*)(Ybf + (size_t)gm * HH + n0 + cb) = o;
    }
}

// ---------------- start head: dot with pw (bf16 h) ----------------
__global__ __launch_bounds__(256) void fhmm_dotpw_kernel(
    const u16* __restrict__ hb, const float* __restrict__ pw,
    const float* __restrict__ pbp, float* __restrict__ p)
{
    int wv = threadIdx.x >> 6;
    int lane = threadIdx.x & 63;
    int s = blockIdx.x * 4 + wv;
    const u16* hr = hb + (size_t)s * HH;
    float acc = 0.f;
    #pragma unroll
    for (int i = 0; i < 4; ++i) acc += bf2f(hr[i * 64 + lane]) * pw[i * 64 + lane];
    #pragma unroll
    for (int d = 32; d; d >>= 1) acc += __shfl_xor(acc, d);
    if (lane == 0) p[s] = acc + pbp[0];
}

// ---------------- in-place log_softmax over a length-8192 vector ----------------
__global__ __launch_bounds__(1024) void fhmm_lsm_vec_kernel(float* __restrict__ p)
{
    __shared__ float red[64];
    int tid = threadIdx.x;
    float m = -1e30f;
    for (int i = tid; i < CST; i += 1024) m = fmaxf(m, p[i]);
    #pragma unroll
    for (int d = 32; d; d >>= 1) m = fmaxf(m, __shfl_xor(m, d));
    if ((tid & 63) == 0) red[tid >> 6] = m;
    __syncthreads();
    if (tid == 0) {
        float mm = red[0];
        for (int q = 1; q < 16; ++q) mm = fmaxf(mm, red[q]);
        red[32] = mm;
    }
    __syncthreads();
    float M = red[32];
    float s = 0.f;
    for (int i = tid; i < CST; i += 1024) s += expf(p[i] - M);
    #pragma unroll
    for (int d = 32; d; d >>= 1) s += __shfl_xor(s, d);
    if ((tid & 63) == 0) red[tid >> 6] = s;
    __syncthreads();
    if (tid == 0) {
        float ss = 0.f;
        for (int q = 0; q < 16; ++q) ss += red[q];
        red[33] = ss;
    }
    __syncthreads();
    float lse = M + logf(red[33]);
    for (int i = tid; i < CST; i += 1024) p[i] -= lse;
}

// ---------------- transition row-lse via MFMA (streaming over 8192 cols) ----------------
__global__ __launch_bounds__(256) void fhmm_trans_lse_mfma(
    const u16* __restrict__ Abf,   // h_state bf16 [8192][256]
    const u16* __restrict__ Bbf,   // next_emb bf16 [8192][256]
    float* __restrict__ lse)
{
    __shared__ char bs[2][32768];
    __shared__ float cmb[4][32], csb[4][32];
    int tid = threadIdx.x;
    int w = tid >> 6, lane = tid & 63;
    int lr = lane & 15, lg = lane >> 4;
    int r0 = blockIdx.x * 32;

    short8 afr[2][8];
    #pragma unroll
    for (int rm = 0; rm < 2; ++rm)
        #pragma unroll
        for (int ks = 0; ks < 8; ++ks)
            afr[rm][ks] = *reinterpret_cast<const short8*>(
                Abf + (size_t)(r0 + rm * 16 + lr) * HH + ks * 32 + lg * 8);

    int soff[8], doff[8];
    #pragma unroll
    for (int i = 0; i < 8; ++i) {
        int c = i * 256 + tid;
        int row = c >> 5, t = c & 31;
        soff[i] = c * 16;
        doff[i] = row * 512 + ((t ^ (row & 7)) << 4);
    }
    const char* Bbytes = reinterpret_cast<const char*>(Bbf);
    #pragma unroll
    for (int i = 0; i < 8; ++i)
        *reinterpret_cast<uint4*>(&bs[0][doff[i]]) =
            *reinterpret_cast<const uint4*>(Bbytes + soff[i]);
    __syncthreads();

    float m0 = -1e30f, s0 = 0.f, m1 = -1e30f, s1 = 0.f;
    int brow = w * 16 + lr;
    int bbase = brow * 512;
    int bswz = (brow & 7) << 4;

    for (int ct = 0; ct < 128; ++ct) {
        uint4 stg[8];
        if (ct < 127) {
            const char* src = Bbytes + (size_t)(ct + 1) * 32768;
            #pragma unroll
            for (int i = 0; i < 8; ++i)
                stg[i] = *reinterpret_cast<const uint4*>(src + soff[i]);
        }
        const char* bsrc = bs[ct & 1];
        f32x4 acc0 = {0.f, 0.f, 0.f, 0.f};
        f32x4 acc1 = {0.f, 0.f, 0.f, 0.f};
        #pragma unroll
        for (int ks = 0; ks < 8; ++ks) {
            short8 bf = *reinterpret_cast<const short8*>(
                bsrc + bbase + ((((ks * 4 + lg)) << 4) ^ bswz));
            acc0 = __builtin_amdgcn_mfma_f32_16x16x32_bf16(bf, afr[0][ks], acc0, 0, 0, 0);
            acc1 = __builtin_amdgcn_mfma_f32_16x16x32_bf16(bf, afr[1][ks], acc1, 0, 0, 0);
        }
        {
            float lm = fmaxf(fmaxf(acc0[0], acc0[1]), fmaxf(acc0[2], acc0[3]));
            float mn = fmaxf(m0, lm);
            s0 = s0 * __expf(m0 - mn)
               + __expf(acc0[0] - mn) + __expf(acc0[1] - mn)
               + __expf(acc0[2] - mn) + __expf(acc0[3] - mn);
            m0 = mn;
        }
        {
            float lm = fmaxf(fmaxf(acc1[0], acc1[1]), fmaxf(acc1[2], acc1[3]));
            float mn = fmaxf(m1, lm);
            s1 = s1 * __expf(m1 - mn)
               + __expf(acc1[0] - mn) + __expf(acc1[1] - mn)
               + __expf(acc1[2] - mn) + __expf(acc1[3] - mn);
            m1 = mn;
        }
        if (ct < 127) {
            char* dstb = bs[(ct + 1) & 1];
            #pragma unroll
            for (int i = 0; i < 8; ++i)
                *reinterpret_cast<uint4*>(dstb + doff[i]) = stg[i];
        }
        __syncthreads();
    }

    #pragma unroll
    for (int d = 16; d < 64; d <<= 1) {
        float m2 = __shfl_xor(m0, d), sx = __shfl_xor(s0, d);
        float mn = fmaxf(m0, m2);
        s0 = s0 * __expf(m0 - mn) + sx * __expf(m2 - mn); m0 = mn;
        m2 = __shfl_xor(m1, d); sx = __shfl_xor(s1, d);
        mn = fmaxf(m1, m2);
        s1 = s1 * __expf(m1 - mn) + sx * __expf(m2 - mn); m1 = mn;
    }
    if (lane < 16) {
        cmb[w][lane] = m0;      csb[w][lane] = s0;
        cmb[w][lane + 16] = m1; csb[w][lane + 16] = s1;
    }
    __syncthreads();
    if (tid < 32) {
        float M = cmb[0][tid], S = csb[0][tid];
        #pragma unroll
        for (int q = 1; q < 4; ++q) {
            float m2 = cmb[q][tid], sx = csb[q][tid];
            float mn = fmaxf(M, m2);
            S = S * __expf(M - mn) + sx * __expf(m2 - mn); M = mn;
        }
        lse[r0 + tid] = M + logf(S);
    }
}

// ---------------- per-(b,t) 64x64 transition-logit blocks, TRANSPOSED bf16 out ----------------
// potsT[blk][j][i] = logits[i=src state][j=dst state]
__global__ __launch_bounds__(256) void fhmm_pots_mfma(
    const u16* __restrict__ Abf, const u16* __restrict__ Bbf,
    const int* __restrict__ text, const int* __restrict__ w2s,
    u16* __restrict__ potsT)
{
    int blk = blockIdx.x;              // b*255 + t
    int b = blk / (TTT - 1), t = blk % (TTT - 1);
    int sr = w2s[text[b * TTT + t] * SPWW];
    int sc = w2s[text[b * TTT + t + 1] * SPWW];
    __shared__ char As_[32768];
    __shared__ char Bs_[32768];
    int tid = threadIdx.x;
    int w = tid >> 6, lane = tid & 63;
    int lr = lane & 15, lg = lane >> 4;

    const char* Asrc = reinterpret_cast<const char*>(Abf + (size_t)sr * HH);
    const char* Bsrc = reinterpret_cast<const char*>(Bbf + (size_t)sc * HH);
    #pragma unroll
    for (int i = 0; i < 8; ++i) {
        int c = i * 256 + tid;
        int row = c >> 5, tt = c & 31;
        int dst = row * 512 + ((tt ^ (row & 7)) << 4);
        *reinterpret_cast<uint4*>(&As_[dst]) = *reinterpret_cast<const uint4*>(Asrc + c * 16);
        *reinterpret_cast<uint4*>(&Bs_[dst]) = *reinterpret_cast<const uint4*>(Bsrc + c * 16);
    }
    __syncthreads();

    short8 bfr[8];
    int brow = w * 16 + lr;
    int bbase = brow * 512;
    int bswz = (brow & 7) << 4;
    #pragma unroll
    for (int ks = 0; ks < 8; ++ks)
        bfr[ks] = *reinterpret_cast<const short8*>(
            Bs_ + bbase + (((ks * 4 + lg) << 4) ^ bswz));

    u16* op = potsT + (size_t)blk * 4096;
    #pragma unroll
    for (int rm = 0; rm < 4; ++rm) {
        f32x4 acc = {0.f, 0.f, 0.f, 0.f};
        int arow = rm * 16 + lr;
        int abase = arow * 512;
        int aswz = (arow & 7) << 4;
        #pragma unroll
        for (int ks = 0; ks < 8; ++ks) {
            short8 af = *reinterpret_cast<const short8*>(
                As_ + abase + (((ks * 4 + lg) << 4) ^ aswz));
            acc = __builtin_amdgcn_mfma_f32_16x16x32_bf16(af, bfr[ks], acc, 0, 0, 0);
        }
        // lane holds C[i = rm*16+lg*4+e][j = w*16+lr]; store potsT[j*64 + i]
        ushort4 o;
        #pragma unroll
        for (int e = 0; e < 4; ++e) ((u16*)&o)[e] = f2bf(acc[e]);
        *(ushort4*)(op + (size_t)(w * 16 + lr) * 64 + rm * 16 + lg * 4) = o;
    }
}

// ---------------- per-class emission GEMM: Ew[v][k] = H_c @ pwT[v] + pb[v] ----------------
__global__ __launch_bounds__(256) void fhmm_ew_mfma(
    const u16* __restrict__ hpre_bf, const u16* __restrict__ pwT,
    const float* __restrict__ pb, const int* __restrict__ wlist,
    const int* __restrict__ counts, const int* __restrict__ offsets,
    float* __restrict__ Ew)
{
    int c = blockIdx.x;
    int cnt = counts[c], off = offsets[c];
    __shared__ char Hs[32768];
    int tid = threadIdx.x, w = tid >> 6, lane = tid & 63, lr = lane & 15, lg = lane >> 4;
    const char* src = (const char*)(hpre_bf + (size_t)c * 64 * HH);
    #pragma unroll
    for (int i = 0; i < 8; ++i) {
        int cc = i * 256 + tid; int row = cc >> 5, tt = cc & 31;
        *(uint4*)&Hs[row * 512 + ((tt ^ (row & 7)) << 4)] = *(const uint4*)(src + cc * 16);
    }
    __syncthreads();
    for (int ch = 0; ch * 64 < cnt; ++ch) {
        int widx = ch * 64 + w * 16 + lr;
        bool valid = widx < cnt;
        int v = valid ? wlist[off + widx] : 0;
        short8 bw[8];
        short8 bz = {0, 0, 0, 0, 0, 0, 0, 0};
        #pragma unroll
        for (int ks = 0; ks < 8; ++ks)
            bw[ks] = valid ? *(const short8*)(pwT + (size_t)v * HH + ks * 32 + lg * 8) : bz;
        float pbv = valid ? pb[v] : 0.f;
        #pragma unroll
        for (int rm = 0; rm < 4; ++rm) {
            f32x4 acc = {0.f, 0.f, 0.f, 0.f};
            int ar = rm * 16 + lr, ab = ar * 512, asw = (ar & 7) << 4;
            #pragma unroll
            for (int ks = 0; ks < 8; ++ks) {
                short8 ah = *(const short8*)(Hs + ab + (((ks * 4 + lg) << 4) ^ asw));
                acc = __builtin_amdgcn_mfma_f32_16x16x32_bf16(ah, bw[ks], acc, 0, 0, 0);
            }
            if (valid) {
                // lane holds Ew[state = rm*16+lg*4+e][word widx] -> Ew[v*64 + state]
                f32x4 o;
                #pragma unroll
                for (int e = 0; e < 4; ++e) o[e] = acc[e] + pbv;
                *(f32x4*)(Ew + (size_t)v * 64 + rm * 16 + lg * 4) = o;
            }
        }
    }
}

// ---------------- class word-lists ----------------
__global__ void fhmm_init_counts_kernel(int* counts, int* cursor) {
    int i = threadIdx.x;
    if (i < NCC) { counts[i] = 0; cursor[i] = 0; }
}
__global__ void fhmm_hist_kernel(const int* __restrict__ w2s, int* counts) {
    int v = blockIdx.x * 256 + threadIdx.x;
    if (v < VV) atomicAdd(&counts[w2s[v * SPWW] >> 6], 1);
}
__global__ void fhmm_offsets_kernel(const int* counts, int* offsets) {
    if (threadIdx.x == 0) {
        int acc = 0;
        for (int c = 0; c < NCC; ++c) { offsets[c] = acc; acc += counts[c]; }
        offsets[NCC] = acc;
    }
}
__global__ void fhmm_scatter_kernel(const int* __restrict__ w2s, const int* offsets,
                                    int* cursor, int* wlist) {
    int v = blockIdx.x * 256 + threadIdx.x;
    if (v < VV) {
        int c = w2s[v * SPWW] >> 6;
        int pos = atomicAdd(&cursor[c], 1);
        wlist[offsets[c] + pos] = v;
    }
}

// ---------------- per-state emission lse ----------------
__global__ __launch_bounds__(64) void fhmm_lse_em_kernel(
    const float* __restrict__ Ew, const int* __restrict__ wlist,
    const int* __restrict__ counts, const int* __restrict__ offsets,
    float* __restrict__ lse_em)
{
    int c = blockIdx.x, k = threadIdx.x;
    int cnt = counts[c], off = offsets[c];
    float m = -1e30f;
    for (int i = 0; i < cnt; ++i) m = fmaxf(m, Ew[wlist[off + i] * 64 + k]);
    float s = 0.f;
    for (int i = 0; i < cnt; ++i) s += __expf(Ew[wlist[off + i] * 64 + k] - m);
    lse_em[c * 64 + k] = (cnt > 0) ? (m + logf(s)) : -1e30f;
}

// ---------------- obs[b,t,k] ----------------
__global__ __launch_bounds__(64) void fhmm_obs_kernel(
    const float* __restrict__ Ew, const float* __restrict__ lse_em,
    const int* __restrict__ text, const int* __restrict__ w2s,
    float* __restrict__ obs)
{
    int i = blockIdx.x;      // b*T + t
    int k = threadIdx.x;
    int v = text[i];
    int s = w2s[v * SPWW + k];
    obs[i * 64 + k] = Ew[v * 64 + k] - lse_em[s];
}

// ---------------- forward scan, depth-8 register prefetch ----------------
__global__ __launch_bounds__(512) void fhmm_scan_kernel(
    const int* __restrict__ text, const int* __restrict__ w2s,
    const float* __restrict__ startv, const float* __restrict__ lse_trans,
    const u16* __restrict__ potsT, const float* __restrict__ obs,
    float* __restrict__ out)
{
    int b = blockIdx.x;
    int tid = threadIdx.x;
    int j = tid >> 3, g = tid & 7;
    __shared__ float al[64];
    __shared__ float alpha_s[64];
    __shared__ int srow_lds[256];
    if (tid < 256) srow_lds[tid] = w2s[text[b * TTT + tid] * SPWW];
    __syncthreads();
    if (g == 0) {
        int s0 = srow_lds[0];
        float a0 = startv[s0 + j] + obs[(size_t)(b * TTT) * 64 + j];
        al[j] = a0 - lse_trans[s0 + j];
    }
    __syncthreads();

    const u16* pbase = potsT + (size_t)b * 255 * 4096;
    uint4 pv[8]; float ob[8], lt[8];
    #pragma unroll
    for (int d = 0; d < 8; ++d) {
        int t = 1 + d;
        pv[d] = *(const uint4*)(pbase + (size_t)(t - 1) * 4096 + j * 64 + g * 8);
        ob[d] = obs[(size_t)(b * TTT + t) * 64 + j];
        lt[d] = lse_trans[srow_lds[t] + j];
    }

    for (int t0 = 1; t0 < 256; t0 += 8) {
        #pragma unroll
        for (int d = 0; d < 8; ++d) {
            int t = t0 + d;
            if (t <= 255) {
                uint4 P = pv[d];
                float obv = ob[d], ltv = lt[d];
                const u16* ps = (const u16*)&P;
                float vv[8];
                #pragma unroll
                for (int ii = 0; ii < 8; ++ii)
                    vv[ii] = al[g * 8 + ii] + bf2f(ps[ii]);
                float m = fmaxf(fmaxf(fmaxf(vv[0], vv[1]), fmaxf(vv[2], vv[3])),
                                fmaxf(fmaxf(vv[4], vv[5]), fmaxf(vv[6], vv[7])));
                float s = 0.f;
                #pragma unroll
                for (int ii = 0; ii < 8; ++ii) s += __expf(vv[ii] - m);
                #pragma unroll
                for (int dd = 1; dd < 8; dd <<= 1) {
                    float m2 = __shfl_xor(m, dd);
                    float s2 = __shfl_xor(s, dd);
                    float mn = fmaxf(m, m2);
                    s = s * __expf(m - mn) + s2 * __expf(m2 - mn);
                    m = mn;
                }
                float alpha_t = m + __logf(s) + obv;
                if (t + 8 <= 255) {
                    int tn = t + 8;
                    pv[d] = *(const uint4*)(pbase + (size_t)(tn - 1) * 4096 + j * 64 + g * 8);
                    ob[d] = obs[(size_t)(b * TTT + tn) * 64 + j];
                    lt[d] = lse_trans[srow_lds[tn] + j];
                }
                __syncthreads();
                if (g == 0) {
                    if (t < 255) al[j] = alpha_t - ltv;
                    else alpha_s[j] = alpha_t;
                }
                __syncthreads();
            }
        }
    }

    if (tid < 64) {
        float a = alpha_s[tid];
        float m = a;
        #pragma unroll
        for (int d = 32; d; d >>= 1) m = fmaxf(m, __shfl_xor(m, d));
        float s = __expf(a - m);
        #pragma unroll
        for (int d = 32; d; d >>= 1) s += __shfl_xor(s, d);
        if (tid == 0) out[b] = m + __logf(s);
    }
}

extern "C" void kernel_launch(void* const* d_in, const int* in_sizes, int n_in,
                              void* d_out, int out_size, void* d_ws, size_t ws_size,
                              hipStream_t stream) {
    const int* text        = (const int*)d_in[0];
    const int* w2s         = (const int*)d_in[1];
    const float* se1_start = (const float*)d_in[2];
    const float* se2_start = (const float*)d_in[3];
    const float* start_w1  = (const float*)d_in[4];
    const float* start_b1  = (const float*)d_in[5];
    const float* start_w2  = (const float*)d_in[6];
    const float* start_b2  = (const float*)d_in[7];
    const float* start_pw  = (const float*)d_in[8];
    const float* start_pb  = (const float*)d_in[9];
    const float* se1_state = (const float*)d_in[10];
    const float* se2_state = (const float*)d_in[11];
    const float* se1_next  = (const float*)d_in[12];
    const float* se2_next  = (const float*)d_in[13];
    const float* trans_w1  = (const float*)d_in[14];
    const float* trans_b1  = (const float*)d_in[15];
    const float* trans_w2  = (const float*)d_in[16];
    const float* trans_b2  = (const float*)d_in[17];
    const float* se1_pre   = (const float*)d_in[18];
    const float* se2_pre   = (const float*)d_in[19];
    const float* term_w1   = (const float*)d_in[20];
    const float* term_b1   = (const float*)d_in[21];
    const float* term_w2   = (const float*)d_in[22];
    const float* term_b2   = (const float*)d_in[23];
    const float* term_pw   = (const float*)d_in[24];
    const float* term_pb   = (const float*)d_in[25];
    float* out = (float*)d_out;

    char* wp = (char*)d_ws;
    auto alloc = [&](size_t bytes) {
        char* p = wp;
        wp += (bytes + 255) & ~(size_t)255;
        return (void*)p;
    };
    u16* emb_bf      = (u16*)alloc((size_t)CST * HH * 2);
    u16* h1_bf       = (u16*)alloc((size_t)CST * HH * 2);
    u16* hstart_bf   = (u16*)alloc((size_t)CST * HH * 2);
    u16* h_state_bf  = (u16*)alloc((size_t)CST * HH * 2);
    u16* h_pre_bf    = (u16*)alloc((size_t)CST * HH * 2);
    u16* next_emb_bf = (u16*)alloc((size_t)CST * HH * 2);
    u16* Wt          = (u16*)alloc((size_t)6 * HH * HH * 2);
    u16* pwT         = (u16*)alloc((size_t)VV * HH * 2);
    float* startv    = (float*)alloc(CST * 4);
    float* lse_trans = (float*)alloc(CST * 4);
    float* lse_em    = (float*)alloc(CST * 4);
    float* Ew        = (float*)alloc((size_t)VV * 64 * 4);
    int* counts      = (int*)alloc(NCC * 4);
    int* offsets     = (int*)alloc((NCC + 4) * 4);
    int* cursor      = (int*)alloc(NCC * 4);
    int* wlist       = (int*)alloc(VV * 4);
    float* obs       = (float*)alloc((size_t)BBB * TTT * 64 * 4);
    u16* potsT       = (u16*)alloc((size_t)BBB * (TTT - 1) * 4096 * 2);

    // weight transposes
    const float* Ws_[6] = {start_w1, start_w2, trans_w1, trans_w2, term_w1, term_w2};
    for (int q = 0; q < 6; ++q)
        hipLaunchKernelGGL(fhmm_wtrans_kernel, dim3(4, 4), 256, 0, stream,
                           Ws_[q], Wt + (size_t)q * HH * HH);
    hipLaunchKernelGGL(fhmm_pwtrans_kernel, dim3((VV + 63) / 64, 4), 256, 0, stream,
                       term_pw, pwT);

    // class word-lists
    hipLaunchKernelGGL(fhmm_init_counts_kernel, dim3(1), 128, 0, stream, counts, cursor);
    hipLaunchKernelGGL(fhmm_hist_kernel, dim3(40), 256, 0, stream, w2s, counts);
    hipLaunchKernelGGL(fhmm_offsets_kernel, dim3(1), 64, 0, stream, counts, offsets);
    hipLaunchKernelGGL(fhmm_scatter_kernel, dim3(40), 256, 0, stream, w2s, offsets, cursor, wlist);

    // next_emb
    hipLaunchKernelGGL(fhmm_emb_bf16_kernel, dim3(8192), 256, 0, stream,
                       se1_next, se2_next, next_emb_bf);

    dim3 mmGrid(128, 4);
    // start head
    hipLaunchKernelGGL(fhmm_emb_bf16_kernel, dim3(8192), 256, 0, stream,
                       se1_start, se2_start, emb_bf);
    hipLaunchKernelGGL(fhmm_mlp_mfma, mmGrid, 256, 0, stream,
                       emb_bf, Wt + 0 * HH * HH, start_b1, (const u16*)nullptr, h1_bf);
    hipLaunchKernelGGL(fhmm_mlp_mfma, mmGrid, 256, 0, stream,
                       h1_bf, Wt + 1 * HH * HH, start_b2, emb_bf, hstart_bf);
    hipLaunchKernelGGL(fhmm_dotpw_kernel, dim3(2048), 256, 0, stream,
                       hstart_bf, start_pw, start_pb, startv);
    hipLaunchKernelGGL(fhmm_lsm_vec_kernel, dim3(1), 1024, 0, stream, startv);

    // state head
    hipLaunchKernelGGL(fhmm_emb_bf16_kernel, dim3(8192), 256, 0, stream,
                       se1_state, se2_state, emb_bf);
    hipLaunchKernelGGL(fhmm_mlp_mfma, mmGrid, 256, 0, stream,
                       emb_bf, Wt + 2 * HH * HH, trans_b1, (const u16*)nullptr, h1_bf);
    hipLaunchKernelGGL(fhmm_mlp_mfma, mmGrid, 256, 0, stream,
                       h1_bf, Wt + 3 * HH * HH, trans_b2, emb_bf, h_state_bf);

    // pre head
    hipLaunchKernelGGL(fhmm_emb_bf16_kernel, dim3(8192), 256, 0, stream,
                       se1_pre, se2_pre, emb_bf);
    hipLaunchKernelGGL(fhmm_mlp_mfma, mmGrid, 256, 0, stream,
                       emb_bf, Wt + 4 * HH * HH, term_b1, (const u16*)nullptr, h1_bf);
    hipLaunchKernelGGL(fhmm_mlp_mfma, mmGrid, 256, 0, stream,
                       h1_bf, Wt + 5 * HH * HH, term_b2, emb_bf, h_pre_bf);

    // transition row-lse + pots
    hipLaunchKernelGGL(fhmm_trans_lse_mfma, dim3(256), 256, 0, stream,
                       h_state_bf, next_emb_bf, lse_trans);
    hipLaunchKernelGGL(fhmm_pots_mfma, dim3(BBB * (TTT - 1)), 256, 0, stream,
                       h_state_bf, next_emb_bf, text, w2s, potsT);

    // emission
    hipLaunchKernelGGL(fhmm_ew_mfma, dim3(NCC), 256, 0, stream,
                       h_pre_bf, pwT, term_pb, wlist, counts, offsets, Ew);
    hipLaunchKernelGGL(fhmm_lse_em_kernel, dim3(NCC), 64, 0, stream,
                       Ew, wlist, counts, offsets, lse_em);
    hipLaunchKernelGGL(fhmm_obs_kernel, dim3(BBB * TTT), 64, 0, stream,
                       Ew, lse_em, text, w2s, obs);

    // forward scan
    hipLaunchKernelGGL(fhmm_scan_kernel, dim3(BBB), 512, 0, stream,
                       text, w2s, startv, lse_trans, potsT, obs, out);
}